// Round 14
// baseline (32.377 us; speedup 1.0000x reference)
//
#include <hip/hip_runtime.h>
#include <hip/hip_bf16.h>

// CombineGraph (GCE-GNN LocalAggregator), B=512, N=64, D=128.
// R14 = R13 resubmitted (container infra died at push; no data). R6 kernel
// with __launch_bounds__(512,2) [was (512,4)] — the ONLY kernel change.
// Tests the VGPR-spill hypothesis: (512,4) caps VGPRs at 128 and the E-phase
// live set is right at that edge; (512,2) lifts the cap to 256.
// Two idempotent dispatches kept so the warm marginal stays comparable to
// R12's 32.25us (decomposition: floor~5.1 + dispatch~1.75 + t_warm~11.8).
//
// Kernel: one block per batch, 512 threads = 8 waves.
// E_k = (H ∘ a_k) H^T, A-frag in registers; 2 barriers; no softmax max-pass.

#define LRELU    0.2f

typedef __bf16 bf16x8 __attribute__((ext_vector_type(8)));
typedef float  f32x4  __attribute__((ext_vector_type(4)));

union FragU { bf16x8 v; unsigned u[4]; uint4 q; };

__device__ __forceinline__ unsigned pk2(float lo, float hi) {
  __hip_bfloat162 t = __float22bfloat162_rn(float2{lo, hi});
  unsigned u;
  __builtin_memcpy(&u, &t, 4);
  return u;
}
__device__ __forceinline__ float bflo(unsigned u) { return __builtin_bit_cast(float, u << 16); }
__device__ __forceinline__ float bfhi(unsigned u) { return __builtin_bit_cast(float, u & 0xffff0000u); }

__global__ __launch_bounds__(512, 2)
void cg_kernel(const int* __restrict__ inputs, const int* __restrict__ adj,
               const float* __restrict__ embedding, const float* __restrict__ attn_a,
               float* __restrict__ out) {
  __shared__ unsigned short Hb[64 * 128];     // h bf16 [i][d], 256B rows, swizzled
  __shared__ unsigned short HbT[128 * 64];    // h^T bf16 [d][j], 128B rows, swizzled
  __shared__ unsigned short Pl[64 * 64];      // P bf16 [i][j], swizzled
  __shared__ float aaL[512];                  // attn_a f32
  __shared__ float redS[64 * 2];              // row-sum partials (per j-half)

  const int b   = blockIdx.x;
  const int tid = threadIdx.x;
  const int w   = tid >> 6;      // 0..7
  const int l   = tid & 63;
  const int lr  = l & 15;
  const int lg  = l >> 4;
  const int it  = w >> 1;        // i-tile 0..3
  const int jh  = w & 1;         // j-half (E), d-half (PV)

  char* HbB  = (char*)Hb;
  char* HbTB = (char*)HbT;
  char* PlB  = (char*)Pl;

  // ---------------- early independent loads ---------------------------------
  const int row = tid >> 3;      // 0..63 (staging row)
  const int c   = tid & 7;       // 16-float chunk
  const int idx = inputs[b * 64 + row];

  int adjv[2][4];
#pragma unroll
  for (int jt2 = 0; jt2 < 2; ++jt2)
#pragma unroll
    for (int r = 0; r < 4; ++r)
      adjv[jt2][r] = adj[b * 4096 + (16 * it + 4 * lg + r) * 64 + 32 * jh + 16 * jt2 + lr];

  const float4* src = (const float4*)(embedding + (long)idx * 128 + c * 16);
  float4 v0 = src[0], v1 = src[1], v2 = src[2], v3 = src[3];
  aaL[tid] = attn_a[tid];

  // ---------------- staging: Hb + HbT ---------------------------------------
  unsigned pk[8];
  pk[0] = pk2(v0.x, v0.y); pk[1] = pk2(v0.z, v0.w);
  pk[2] = pk2(v1.x, v1.y); pk[3] = pk2(v1.z, v1.w);
  pk[4] = pk2(v2.x, v2.y); pk[5] = pk2(v2.z, v2.w);
  pk[6] = pk2(v3.x, v3.y); pk[7] = pk2(v3.z, v3.w);
  const int rswz = (row & 7) << 4;
  *(uint4*)(HbB + ((row * 256 + c * 32)      ^ rswz)) = uint4{pk[0], pk[1], pk[2], pk[3]};
  *(uint4*)(HbB + ((row * 256 + c * 32 + 16) ^ rswz)) = uint4{pk[4], pk[5], pk[6], pk[7]};
  // transpose staging: rotate e by 3*c so d&7 spans all 8 values across lanes
#pragma unroll
  for (int s = 0; s < 16; ++s) {
    int e = (s + 3 * c) & 15;
    int d = c * 16 + e;
    unsigned short hv = (unsigned short)((e & 1) ? (pk[e >> 1] >> 16) : (pk[e >> 1] & 0xffffu));
    *(unsigned short*)(HbTB + ((d * 128 + row * 2) ^ ((d & 7) << 4))) = hv;
  }
  __syncthreads();   // (1) Hb + HbT + aaL visible

  // ---------------- E phase: A-frag (h∘a_k) built in registers --------------
  f32x4 acc[4][2];
#pragma unroll
  for (int k = 0; k < 4; ++k)
#pragma unroll
    for (int jt2 = 0; jt2 < 2; ++jt2) acc[k][jt2] = f32x4{0.f, 0.f, 0.f, 0.f};

  const int arow = 16 * it + lr;
  const int aswz = (lr & 7) << 4;        // row&7 == lr&7 for rows 16*t+lr

#pragma unroll
  for (int kc = 0; kc < 4; ++kc) {
    const int dsl = kc * 32 + lg * 8;    // this lane's 8-elem d-slice
    uint4 ha = *(const uint4*)(HbB + ((arow * 256 + dsl * 2) ^ aswz));
    float hfa[8];
    hfa[0] = bflo(ha.x); hfa[1] = bfhi(ha.x);
    hfa[2] = bflo(ha.y); hfa[3] = bfhi(ha.y);
    hfa[4] = bflo(ha.z); hfa[5] = bfhi(ha.z);
    hfa[6] = bflo(ha.w); hfa[7] = bfhi(ha.w);
    FragU bf0, bf1;
    {
      int jr0 = 32 * jh + lr;
      int jr1 = 32 * jh + 16 + lr;
      bf0.q = *(const uint4*)(HbB + ((jr0 * 256 + dsl * 2) ^ aswz));
      bf1.q = *(const uint4*)(HbB + ((jr1 * 256 + dsl * 2) ^ aswz));
    }
#pragma unroll
    for (int k = 0; k < 4; ++k) {
      float4 a0 = *(const float4*)&aaL[k * 128 + dsl];
      float4 a1 = *(const float4*)&aaL[k * 128 + dsl + 4];
      FragU afr;
      afr.u[0] = pk2(hfa[0] * a0.x, hfa[1] * a0.y);
      afr.u[1] = pk2(hfa[2] * a0.z, hfa[3] * a0.w);
      afr.u[2] = pk2(hfa[4] * a1.x, hfa[5] * a1.y);
      afr.u[3] = pk2(hfa[6] * a1.z, hfa[7] * a1.w);
      acc[k][0] = __builtin_amdgcn_mfma_f32_16x16x32_bf16(afr.v, bf0.v, acc[k][0], 0, 0, 0);
      acc[k][1] = __builtin_amdgcn_mfma_f32_16x16x32_bf16(afr.v, bf1.v, acc[k][1], 0, 0, 0);
    }
  }

  // ---------------- selection + leakyrelu + exp (no max pass) ---------------
  float p[2][4];
#pragma unroll
  for (int jt2 = 0; jt2 < 2; ++jt2)
#pragma unroll
    for (int r = 0; r < 4; ++r) {
      int av = adjv[jt2][r];
      float s = acc[0][jt2][r];
      s = (av == 2) ? acc[1][jt2][r] : s;
      s = (av == 3) ? acc[2][jt2][r] : s;
      s = (av == 4) ? acc[3][jt2][r] : s;
      float sl = s > 0.f ? s : LRELU * s;
      p[jt2][r] = (av != 0) ? __expf(sl) : 0.f;
    }
#pragma unroll
  for (int r = 0; r < 4; ++r) {
    int i = 16 * it + 4 * lg + r;
    int iswz = (i & 7) << 4;
    *(unsigned short*)(PlB + ((i * 128 + (32 * jh + lr) * 2)      ^ iswz)) = (unsigned short)(pk2(p[0][r], p[0][r]) & 0xffffu);
    *(unsigned short*)(PlB + ((i * 128 + (32 * jh + 16 + lr) * 2) ^ iswz)) = (unsigned short)(pk2(p[1][r], p[1][r]) & 0xffffu);
    float ss = p[0][r] + p[1][r];
    ss += __shfl_xor(ss, 1);
    ss += __shfl_xor(ss, 2);
    ss += __shfl_xor(ss, 4);
    ss += __shfl_xor(ss, 8);
    if (lr == 0) redS[i * 2 + jh] = ss;
  }
  __syncthreads();   // (2) Pl + redS ready
  float z4[4];
#pragma unroll
  for (int r = 0; r < 4; ++r) {
    int i = 16 * it + 4 * lg + r;
    z4[r] = redS[i * 2] + redS[i * 2 + 1];
  }

  // ---------------- PV: out = P · H  (wave: rows 16it.., d-half jh) ---------
  FragU afrP[2];
#pragma unroll
  for (int kc2 = 0; kc2 < 2; ++kc2) {
    int prow = 16 * it + lr;
    afrP[kc2].q = *(const uint4*)(PlB + ((prow * 128 + (kc2 * 32 + lg * 8) * 2) ^ aswz));
  }
  f32x4 pv[4];
#pragma unroll
  for (int dtl = 0; dtl < 4; ++dtl) pv[dtl] = f32x4{0.f, 0.f, 0.f, 0.f};
#pragma unroll
  for (int dtl = 0; dtl < 4; ++dtl) {
#pragma unroll
    for (int kc2 = 0; kc2 < 2; ++kc2) {
      int drow = 64 * jh + 16 * dtl + lr;
      FragU bfr;
      bfr.q = *(const uint4*)(HbTB + ((drow * 128 + (kc2 * 32 + lg * 8) * 2) ^ ((drow & 7) << 4)));
      pv[dtl] = __builtin_amdgcn_mfma_f32_16x16x32_bf16(afrP[kc2].v, bfr.v, pv[dtl], 0, 0, 0);
    }
  }

  // ---------------- epilogue ------------------------------------------------
#pragma unroll
  for (int r = 0; r < 4; ++r) {
    int i = 16 * it + 4 * lg + r;
    float invz = 1.0f / z4[r];
#pragma unroll
    for (int dtl = 0; dtl < 4; ++dtl) {
      int d = 64 * jh + 16 * dtl + lr;
      out[(b * 64 + i) * 128 + d] = pv[dtl][r] * invz;
    }
  }
}

extern "C" void kernel_launch(void* const* d_in, const int* in_sizes, int n_in,
                              void* d_out, int out_size, void* d_ws, size_t ws_size,
                              hipStream_t stream) {
  (void)in_sizes; (void)n_in; (void)d_ws; (void)ws_size; (void)out_size;
  const int*   inputs    = (const int*)d_in[0];
  const int*   adj       = (const int*)d_in[1];
  // d_in[2] = mask_item, d_in[3] = item — unused by the reference output
  const float* embedding = (const float*)d_in[4];
  const float* attn_a    = (const float*)d_in[5];
  float*       out       = (float*)d_out;
  // PROBE STRUCTURE KEPT: two identical idempotent dispatches.
  // Compare dur to R12's 32.25us: <=27 -> spills were real; ~32 -> H1 dead.
  cg_kernel<<<dim3(512), dim3(512), 0, stream>>>(inputs, adj, embedding, attn_a, out);
  cg_kernel<<<dim3(512), dim3(512), 0, stream>>>(inputs, adj, embedding, attn_a, out);
}

// Round 18
// 17.510 us; speedup vs baseline: 1.8491x; 1.8491x over previous
//
#include <hip/hip_runtime.h>
#include <hip/hip_bf16.h>

// CombineGraph (GCE-GNN LocalAggregator), B=512, N=64, D=128.
// R18 = R15/R16/R17 resubmitted (same container unresponsive at push x3;
// failure precedes code execution — not kernel-caused).
// LDS-issue reduction (~-24 LDS instr/thread vs R6):
//  (1) attn_a staged as bf16 (aaB): 1 b128 read per (kc,k) instead of 2.
//  (2) staging remap: thread = (row-pair, 8-d chunk) -> HbT written as 8 b32
//      (packed j-pairs) instead of 16 b16. New XOR swizzle on HbT:
//      ((d&7)^((d>>3)&7))<<4 keeps writes AND PV reads ~2-way (free).
// One block per batch, 512 threads = 8 waves; 2 barriers; no softmax max-pass.

#define LRELU    0.2f

typedef __bf16 bf16x8 __attribute__((ext_vector_type(8)));
typedef float  f32x4  __attribute__((ext_vector_type(4)));

union FragU { bf16x8 v; unsigned u[4]; uint4 q; };

__device__ __forceinline__ unsigned pk2(float lo, float hi) {
  __hip_bfloat162 t = __float22bfloat162_rn(float2{lo, hi});
  unsigned u;
  __builtin_memcpy(&u, &t, 4);
  return u;
}
__device__ __forceinline__ float bflo(unsigned u) { return __builtin_bit_cast(float, u << 16); }
__device__ __forceinline__ float bfhi(unsigned u) { return __builtin_bit_cast(float, u & 0xffff0000u); }

__device__ __forceinline__ int swzT(int d) {          // HbT swizzle selector
  return (((d & 7) ^ ((d >> 3) & 7)) << 4);
}

__global__ __launch_bounds__(512, 4)
void cg_kernel(const int* __restrict__ inputs, const int* __restrict__ adj,
               const float* __restrict__ embedding, const float* __restrict__ attn_a,
               float* __restrict__ out) {
  __shared__ unsigned short Hb[64 * 128];     // h bf16 [i][d], 256B rows, ^((i&7)<<4)
  __shared__ unsigned short HbT[128 * 64];    // h^T bf16 [d][j], 128B rows, ^swzT(d)
  __shared__ unsigned short Pl[64 * 64];      // P bf16 [i][j], ^((i&7)<<4)
  __shared__ unsigned short aaB[4 * 128];     // attn_a bf16 [k][d]
  __shared__ float redS[64 * 2];              // row-sum partials (per j-half)

  const int b   = blockIdx.x;
  const int tid = threadIdx.x;
  const int w   = tid >> 6;      // 0..7
  const int l   = tid & 63;
  const int lr  = l & 15;
  const int lg  = l >> 4;
  const int it  = w >> 1;        // i-tile 0..3
  const int jh  = w & 1;         // j-half (E), d-half (PV)

  char* HbB  = (char*)Hb;
  char* HbTB = (char*)HbT;
  char* PlB  = (char*)Pl;
  char* aaBB = (char*)aaB;

  // ---------------- early independent loads ---------------------------------
  const int rp = tid >> 4;       // row-pair 0..31
  const int c8 = tid & 15;       // 8-d chunk 0..15
  const int2 idx2 = *(const int2*)&inputs[b * 64 + 2 * rp];

  int adjv[2][4];
#pragma unroll
  for (int jt2 = 0; jt2 < 2; ++jt2)
#pragma unroll
    for (int r = 0; r < 4; ++r)
      adjv[jt2][r] = adj[b * 4096 + (16 * it + 4 * lg + r) * 64 + 32 * jh + 16 * jt2 + lr];

  const float4* s0 = (const float4*)(embedding + (long)idx2.x * 128 + c8 * 8);
  const float4* s1 = (const float4*)(embedding + (long)idx2.y * 128 + c8 * 8);
  float4 r0a = s0[0], r0b = s0[1];     // row 2rp,   d in [8c8, 8c8+8)
  float4 r1a = s1[0], r1b = s1[1];     // row 2rp+1, same d range

  if (tid < 256) {                     // attn_a -> bf16 LDS (512 floats)
    float2 av = *(const float2*)&attn_a[2 * tid];
    *(unsigned*)(aaBB + 4 * tid) = pk2(av.x, av.y);
  }

  // ---------------- staging: Hb (b128 x2) + HbT (b32 x8) --------------------
  unsigned p0[4], p1[4];
  p0[0] = pk2(r0a.x, r0a.y); p0[1] = pk2(r0a.z, r0a.w);
  p0[2] = pk2(r0b.x, r0b.y); p0[3] = pk2(r0b.z, r0b.w);
  p1[0] = pk2(r1a.x, r1a.y); p1[1] = pk2(r1a.z, r1a.w);
  p1[2] = pk2(r1b.x, r1b.y); p1[3] = pk2(r1b.z, r1b.w);
  const int r0 = 2 * rp, r1 = 2 * rp + 1;
  *(uint4*)(HbB + ((r0 * 256 + c8 * 16) ^ ((r0 & 7) << 4))) = uint4{p0[0], p0[1], p0[2], p0[3]};
  *(uint4*)(HbB + ((r1 * 256 + c8 * 16) ^ ((r1 & 7) << 4))) = uint4{p1[0], p1[1], p1[2], p1[3]};
#pragma unroll
  for (int e = 0; e < 8; ++e) {
    int d = 8 * c8 + e;
    unsigned v0 = (e & 1) ? (p0[e >> 1] >> 16) : (p0[e >> 1] & 0xffffu);
    unsigned v1 = (e & 1) ? (p1[e >> 1] & 0xffff0000u) : (p1[e >> 1] << 16);
    *(unsigned*)(HbTB + ((d * 128 + 4 * rp) ^ swzT(d))) = v0 | v1;
  }
  __syncthreads();   // (1) Hb + HbT + aaB visible

  // ---------------- E phase: A-frag (h∘a_k) built in registers --------------
  f32x4 acc[4][2];
#pragma unroll
  for (int k = 0; k < 4; ++k)
#pragma unroll
    for (int jt2 = 0; jt2 < 2; ++jt2) acc[k][jt2] = f32x4{0.f, 0.f, 0.f, 0.f};

  const int arow = 16 * it + lr;
  const int aswz = (lr & 7) << 4;        // row&7 == lr&7 for rows 16*t+lr

#pragma unroll
  for (int kc = 0; kc < 4; ++kc) {
    const int dsl = kc * 32 + lg * 8;    // this lane's 8-elem d-slice
    uint4 ha = *(const uint4*)(HbB + ((arow * 256 + dsl * 2) ^ aswz));
    float hfa[8];
    hfa[0] = bflo(ha.x); hfa[1] = bfhi(ha.x);
    hfa[2] = bflo(ha.y); hfa[3] = bfhi(ha.y);
    hfa[4] = bflo(ha.z); hfa[5] = bfhi(ha.z);
    hfa[6] = bflo(ha.w); hfa[7] = bfhi(ha.w);
    FragU bf0, bf1;
    {
      int jr0 = 32 * jh + lr;
      int jr1 = 32 * jh + 16 + lr;
      bf0.q = *(const uint4*)(HbB + ((jr0 * 256 + dsl * 2) ^ aswz));
      bf1.q = *(const uint4*)(HbB + ((jr1 * 256 + dsl * 2) ^ aswz));
    }
#pragma unroll
    for (int k = 0; k < 4; ++k) {
      uint4 au = *(const uint4*)(aaBB + (k * 256 + dsl * 2));   // 8 bf16 a-vals
      float af[8];
      af[0] = bflo(au.x); af[1] = bfhi(au.x);
      af[2] = bflo(au.y); af[3] = bfhi(au.y);
      af[4] = bflo(au.z); af[5] = bfhi(au.z);
      af[6] = bflo(au.w); af[7] = bfhi(au.w);
      FragU afr;
      afr.u[0] = pk2(hfa[0] * af[0], hfa[1] * af[1]);
      afr.u[1] = pk2(hfa[2] * af[2], hfa[3] * af[3]);
      afr.u[2] = pk2(hfa[4] * af[4], hfa[5] * af[5]);
      afr.u[3] = pk2(hfa[6] * af[6], hfa[7] * af[7]);
      acc[k][0] = __builtin_amdgcn_mfma_f32_16x16x32_bf16(afr.v, bf0.v, acc[k][0], 0, 0, 0);
      acc[k][1] = __builtin_amdgcn_mfma_f32_16x16x32_bf16(afr.v, bf1.v, acc[k][1], 0, 0, 0);
    }
  }

  // ---------------- selection + leakyrelu + exp (no max pass) ---------------
  float p[2][4];
#pragma unroll
  for (int jt2 = 0; jt2 < 2; ++jt2)
#pragma unroll
    for (int r = 0; r < 4; ++r) {
      int av = adjv[jt2][r];
      float s = acc[0][jt2][r];
      s = (av == 2) ? acc[1][jt2][r] : s;
      s = (av == 3) ? acc[2][jt2][r] : s;
      s = (av == 4) ? acc[3][jt2][r] : s;
      float sl = s > 0.f ? s : LRELU * s;
      p[jt2][r] = (av != 0) ? __expf(sl) : 0.f;
    }
#pragma unroll
  for (int r = 0; r < 4; ++r) {
    int i = 16 * it + 4 * lg + r;
    int iswz = (i & 7) << 4;
    *(unsigned short*)(PlB + ((i * 128 + (32 * jh + lr) * 2)      ^ iswz)) = (unsigned short)(pk2(p[0][r], p[0][r]) & 0xffffu);
    *(unsigned short*)(PlB + ((i * 128 + (32 * jh + 16 + lr) * 2) ^ iswz)) = (unsigned short)(pk2(p[1][r], p[1][r]) & 0xffffu);
    float ss = p[0][r] + p[1][r];
    ss += __shfl_xor(ss, 1);
    ss += __shfl_xor(ss, 2);
    ss += __shfl_xor(ss, 4);
    ss += __shfl_xor(ss, 8);
    if (lr == 0) redS[i * 2 + jh] = ss;
  }
  __syncthreads();   // (2) Pl + redS ready
  float z4[4];
#pragma unroll
  for (int r = 0; r < 4; ++r) {
    int i = 16 * it + 4 * lg + r;
    float2 sv = *(const float2*)&redS[i * 2];
    z4[r] = sv.x + sv.y;
  }

  // ---------------- PV: out = P · H  (wave: rows 16it.., d-half jh) ---------
  FragU afrP[2];
#pragma unroll
  for (int kc2 = 0; kc2 < 2; ++kc2) {
    int prow = 16 * it + lr;
    afrP[kc2].q = *(const uint4*)(PlB + ((prow * 128 + (kc2 * 32 + lg * 8) * 2) ^ aswz));
  }
  f32x4 pv[4];
#pragma unroll
  for (int dtl = 0; dtl < 4; ++dtl) pv[dtl] = f32x4{0.f, 0.f, 0.f, 0.f};
#pragma unroll
  for (int dtl = 0; dtl < 4; ++dtl) {
#pragma unroll
    for (int kc2 = 0; kc2 < 2; ++kc2) {
      int drow = 64 * jh + 16 * dtl + lr;
      FragU bfr;
      bfr.q = *(const uint4*)(HbTB + ((drow * 128 + (kc2 * 32 + lg * 8) * 2) ^ swzT(drow)));
      pv[dtl] = __builtin_amdgcn_mfma_f32_16x16x32_bf16(afrP[kc2].v, bfr.v, pv[dtl], 0, 0, 0);
    }
  }

  // ---------------- epilogue ------------------------------------------------
#pragma unroll
  for (int r = 0; r < 4; ++r) {
    int i = 16 * it + 4 * lg + r;
    float invz = 1.0f / z4[r];
#pragma unroll
    for (int dtl = 0; dtl < 4; ++dtl) {
      int d = 64 * jh + 16 * dtl + lr;
      out[(b * 64 + i) * 128 + d] = pv[dtl][r] * invz;
    }
  }
}

extern "C" void kernel_launch(void* const* d_in, const int* in_sizes, int n_in,
                              void* d_out, int out_size, void* d_ws, size_t ws_size,
                              hipStream_t stream) {
  (void)in_sizes; (void)n_in; (void)d_ws; (void)ws_size; (void)out_size;
  const int*   inputs    = (const int*)d_in[0];
  const int*   adj       = (const int*)d_in[1];
  // d_in[2] = mask_item, d_in[3] = item — unused by the reference output
  const float* embedding = (const float*)d_in[4];
  const float* attn_a    = (const float*)d_in[5];
  float*       out       = (float*)d_out;
  cg_kernel<<<dim3(512), dim3(512), 0, stream>>>(inputs, adj, embedding, attn_a, out);
}

// Round 19
// 16.844 us; speedup vs baseline: 1.9221x; 1.0395x over previous
//
#include <hip/hip_runtime.h>
#include <hip/hip_bf16.h>

// CombineGraph (GCE-GNN LocalAggregator), B=512, N=64, D=128.
// R19 = R18 + softmax-sum via MFMA ones-column (Z = P·1) replacing the
// 16 ds_bpermute (__shfl_xor) + redS ops — all LDS-pipe traffic at the
// measured ~50ns/op. C-layout row=4lg+r delivers Z[i] to exactly the lane
// that normalizes row i. 2 barriers; no softmax max-pass.
//
// Carried from R18: aaB bf16 staging (1 b128/ (kc,k)), row-pair HbT b32
// staging with bijective swizzle ((d&7)^((d>>3)&7))<<4.

#define LRELU    0.2f

typedef __bf16 bf16x8 __attribute__((ext_vector_type(8)));
typedef float  f32x4  __attribute__((ext_vector_type(4)));

union FragU { bf16x8 v; unsigned u[4]; uint4 q; };

__device__ __forceinline__ unsigned pk2(float lo, float hi) {
  __hip_bfloat162 t = __float22bfloat162_rn(float2{lo, hi});
  unsigned u;
  __builtin_memcpy(&u, &t, 4);
  return u;
}
__device__ __forceinline__ float bflo(unsigned u) { return __builtin_bit_cast(float, u << 16); }
__device__ __forceinline__ float bfhi(unsigned u) { return __builtin_bit_cast(float, u & 0xffff0000u); }

__device__ __forceinline__ int swzT(int d) {          // HbT swizzle selector
  return (((d & 7) ^ ((d >> 3) & 7)) << 4);
}

__global__ __launch_bounds__(512, 4)
void cg_kernel(const int* __restrict__ inputs, const int* __restrict__ adj,
               const float* __restrict__ embedding, const float* __restrict__ attn_a,
               float* __restrict__ out) {
  __shared__ unsigned short Hb[64 * 128];     // h bf16 [i][d], 256B rows, ^((i&7)<<4)
  __shared__ unsigned short HbT[128 * 64];    // h^T bf16 [d][j], 128B rows, ^swzT(d)
  __shared__ unsigned short Pl[64 * 64];      // P bf16 [i][j], ^((i&7)<<4)
  __shared__ unsigned short aaB[4 * 128];     // attn_a bf16 [k][d]

  const int b   = blockIdx.x;
  const int tid = threadIdx.x;
  const int w   = tid >> 6;      // 0..7
  const int l   = tid & 63;
  const int lr  = l & 15;
  const int lg  = l >> 4;
  const int it  = w >> 1;        // i-tile 0..3
  const int jh  = w & 1;         // j-half (E), d-half (PV)

  char* HbB  = (char*)Hb;
  char* HbTB = (char*)HbT;
  char* PlB  = (char*)Pl;
  char* aaBB = (char*)aaB;

  // ---------------- early independent loads ---------------------------------
  const int rp = tid >> 4;       // row-pair 0..31
  const int c8 = tid & 15;       // 8-d chunk 0..15
  const int2 idx2 = *(const int2*)&inputs[b * 64 + 2 * rp];

  int adjv[2][4];
#pragma unroll
  for (int jt2 = 0; jt2 < 2; ++jt2)
#pragma unroll
    for (int r = 0; r < 4; ++r)
      adjv[jt2][r] = adj[b * 4096 + (16 * it + 4 * lg + r) * 64 + 32 * jh + 16 * jt2 + lr];

  const float4* s0 = (const float4*)(embedding + (long)idx2.x * 128 + c8 * 8);
  const float4* s1 = (const float4*)(embedding + (long)idx2.y * 128 + c8 * 8);
  float4 r0a = s0[0], r0b = s0[1];     // row 2rp,   d in [8c8, 8c8+8)
  float4 r1a = s1[0], r1b = s1[1];     // row 2rp+1, same d range

  if (tid < 256) {                     // attn_a -> bf16 LDS (512 floats)
    float2 av = *(const float2*)&attn_a[2 * tid];
    *(unsigned*)(aaBB + 4 * tid) = pk2(av.x, av.y);
  }

  // ---------------- staging: Hb (b128 x2) + HbT (b32 x8) --------------------
  unsigned p0[4], p1[4];
  p0[0] = pk2(r0a.x, r0a.y); p0[1] = pk2(r0a.z, r0a.w);
  p0[2] = pk2(r0b.x, r0b.y); p0[3] = pk2(r0b.z, r0b.w);
  p1[0] = pk2(r1a.x, r1a.y); p1[1] = pk2(r1a.z, r1a.w);
  p1[2] = pk2(r1b.x, r1b.y); p1[3] = pk2(r1b.z, r1b.w);
  const int r0 = 2 * rp, r1 = 2 * rp + 1;
  *(uint4*)(HbB + ((r0 * 256 + c8 * 16) ^ ((r0 & 7) << 4))) = uint4{p0[0], p0[1], p0[2], p0[3]};
  *(uint4*)(HbB + ((r1 * 256 + c8 * 16) ^ ((r1 & 7) << 4))) = uint4{p1[0], p1[1], p1[2], p1[3]};
#pragma unroll
  for (int e = 0; e < 8; ++e) {
    int d = 8 * c8 + e;
    unsigned v0 = (e & 1) ? (p0[e >> 1] >> 16) : (p0[e >> 1] & 0xffffu);
    unsigned v1 = (e & 1) ? (p1[e >> 1] & 0xffff0000u) : (p1[e >> 1] << 16);
    *(unsigned*)(HbTB + ((d * 128 + 4 * rp) ^ swzT(d))) = v0 | v1;
  }
  __syncthreads();   // (1) Hb + HbT + aaB visible

  // ---------------- E phase: A-frag (h∘a_k) built in registers --------------
  f32x4 acc[4][2];
#pragma unroll
  for (int k = 0; k < 4; ++k)
#pragma unroll
    for (int jt2 = 0; jt2 < 2; ++jt2) acc[k][jt2] = f32x4{0.f, 0.f, 0.f, 0.f};

  const int arow = 16 * it + lr;
  const int aswz = (lr & 7) << 4;        // row&7 == lr&7 for rows 16*t+lr

#pragma unroll
  for (int kc = 0; kc < 4; ++kc) {
    const int dsl = kc * 32 + lg * 8;    // this lane's 8-elem d-slice
    uint4 ha = *(const uint4*)(HbB + ((arow * 256 + dsl * 2) ^ aswz));
    float hfa[8];
    hfa[0] = bflo(ha.x); hfa[1] = bfhi(ha.x);
    hfa[2] = bflo(ha.y); hfa[3] = bfhi(ha.y);
    hfa[4] = bflo(ha.z); hfa[5] = bfhi(ha.z);
    hfa[6] = bflo(ha.w); hfa[7] = bfhi(ha.w);
    FragU bf0, bf1;
    {
      int jr0 = 32 * jh + lr;
      int jr1 = 32 * jh + 16 + lr;
      bf0.q = *(const uint4*)(HbB + ((jr0 * 256 + dsl * 2) ^ aswz));
      bf1.q = *(const uint4*)(HbB + ((jr1 * 256 + dsl * 2) ^ aswz));
    }
#pragma unroll
    for (int k = 0; k < 4; ++k) {
      uint4 au = *(const uint4*)(aaBB + (k * 256 + dsl * 2));   // 8 bf16 a-vals
      float af[8];
      af[0] = bflo(au.x); af[1] = bfhi(au.x);
      af[2] = bflo(au.y); af[3] = bfhi(au.y);
      af[4] = bflo(au.z); af[5] = bfhi(au.z);
      af[6] = bflo(au.w); af[7] = bfhi(au.w);
      FragU afr;
      afr.u[0] = pk2(hfa[0] * af[0], hfa[1] * af[1]);
      afr.u[1] = pk2(hfa[2] * af[2], hfa[3] * af[3]);
      afr.u[2] = pk2(hfa[4] * af[4], hfa[5] * af[5]);
      afr.u[3] = pk2(hfa[6] * af[6], hfa[7] * af[7]);
      acc[k][0] = __builtin_amdgcn_mfma_f32_16x16x32_bf16(afr.v, bf0.v, acc[k][0], 0, 0, 0);
      acc[k][1] = __builtin_amdgcn_mfma_f32_16x16x32_bf16(afr.v, bf1.v, acc[k][1], 0, 0, 0);
    }
  }

  // ---------------- selection + leakyrelu + exp (no max pass) ---------------
  float p[2][4];
#pragma unroll
  for (int jt2 = 0; jt2 < 2; ++jt2)
#pragma unroll
    for (int r = 0; r < 4; ++r) {
      int av = adjv[jt2][r];
      float s = acc[0][jt2][r];
      s = (av == 2) ? acc[1][jt2][r] : s;
      s = (av == 3) ? acc[2][jt2][r] : s;
      s = (av == 4) ? acc[3][jt2][r] : s;
      float sl = s > 0.f ? s : LRELU * s;
      p[jt2][r] = (av != 0) ? __expf(sl) : 0.f;
    }
#pragma unroll
  for (int r = 0; r < 4; ++r) {
    int i = 16 * it + 4 * lg + r;
    int iswz = (i & 7) << 4;
    *(unsigned short*)(PlB + ((i * 128 + (32 * jh + lr) * 2)      ^ iswz)) = (unsigned short)(pk2(p[0][r], p[0][r]) & 0xffffu);
    *(unsigned short*)(PlB + ((i * 128 + (32 * jh + 16 + lr) * 2) ^ iswz)) = (unsigned short)(pk2(p[1][r], p[1][r]) & 0xffffu);
  }
  __syncthreads();   // (2) Pl ready

  // ---------------- PV + Z: out = P · H, Z = P · 1 (MFMA ones-column) ------
  FragU afrP[2];
#pragma unroll
  for (int kc2 = 0; kc2 < 2; ++kc2) {
    int prow = 16 * it + lr;
    afrP[kc2].q = *(const uint4*)(PlB + ((prow * 128 + (kc2 * 32 + lg * 8) * 2) ^ aswz));
  }
  // Z[i] = sum_j P[i][j]: B-frag of bf16 ones (1.0 = 0x3F80), built in regs.
  FragU ones;
  ones.u[0] = 0x3F803F80u; ones.u[1] = 0x3F803F80u;
  ones.u[2] = 0x3F803F80u; ones.u[3] = 0x3F803F80u;
  f32x4 zf = f32x4{0.f, 0.f, 0.f, 0.f};
  zf = __builtin_amdgcn_mfma_f32_16x16x32_bf16(afrP[0].v, ones.v, zf, 0, 0, 0);
  zf = __builtin_amdgcn_mfma_f32_16x16x32_bf16(afrP[1].v, ones.v, zf, 0, 0, 0);
  // C layout row = 4*lg + r  ->  zf[r] = Z[16*it + 4*lg + r]  (matches epilogue)

  f32x4 pv[4];
#pragma unroll
  for (int dtl = 0; dtl < 4; ++dtl) pv[dtl] = f32x4{0.f, 0.f, 0.f, 0.f};
#pragma unroll
  for (int dtl = 0; dtl < 4; ++dtl) {
#pragma unroll
    for (int kc2 = 0; kc2 < 2; ++kc2) {
      int drow = 64 * jh + 16 * dtl + lr;
      FragU bfr;
      bfr.q = *(const uint4*)(HbTB + ((drow * 128 + (kc2 * 32 + lg * 8) * 2) ^ swzT(drow)));
      pv[dtl] = __builtin_amdgcn_mfma_f32_16x16x32_bf16(afrP[kc2].v, bfr.v, pv[dtl], 0, 0, 0);
    }
  }

  // ---------------- epilogue ------------------------------------------------
#pragma unroll
  for (int r = 0; r < 4; ++r) {
    int i = 16 * it + 4 * lg + r;
    float invz = 1.0f / zf[r];
#pragma unroll
    for (int dtl = 0; dtl < 4; ++dtl) {
      int d = 64 * jh + 16 * dtl + lr;
      out[(b * 64 + i) * 128 + d] = pv[dtl][r] * invz;
    }
  }
}

extern "C" void kernel_launch(void* const* d_in, const int* in_sizes, int n_in,
                              void* d_out, int out_size, void* d_ws, size_t ws_size,
                              hipStream_t stream) {
  (void)in_sizes; (void)n_in; (void)d_ws; (void)ws_size; (void)out_size;
  const int*   inputs    = (const int*)d_in[0];
  const int*   adj       = (const int*)d_in[1];
  // d_in[2] = mask_item, d_in[3] = item — unused by the reference output
  const float* embedding = (const float*)d_in[4];
  const float* attn_a    = (const float*)d_in[5];
  float*       out       = (float*)d_out;
  cg_kernel<<<dim3(512), dim3(512), 0, stream>>>(inputs, adj, embedding, attn_a, out);
}